// Round 1
// baseline (984.843 us; speedup 1.0000x reference)
//
#include <hip/hip_runtime.h>
#include <math.h>

#define DIM 256
#define NHEAD 8
#define NLVL 4
#define NPT 4
#define HDIM 32
#define FFDIM 1024
#define BATCH 4
#define SEQ 5440
#define MTOK (BATCH * SEQ)   // 21760

// ---------------------------------------------------------------------------
// LayerNorm (+ optional additive term): one block per token, 256 threads.
// ---------------------------------------------------------------------------
__global__ __launch_bounds__(256) void ln_kernel(
    const float* __restrict__ x, const float* __restrict__ w,
    const float* __restrict__ bvec, const float* __restrict__ addend,
    float* __restrict__ out)
{
    int token = blockIdx.x;
    int t = threadIdx.x;
    float v = x[(size_t)token * DIM + t];

    float s = v, s2 = v * v;
    #pragma unroll
    for (int o = 32; o > 0; o >>= 1) {
        s  += __shfl_down(s, o);
        s2 += __shfl_down(s2, o);
    }
    __shared__ float ps[4], ps2[4];
    int wid = t >> 6, lane = t & 63;
    if (lane == 0) { ps[wid] = s; ps2[wid] = s2; }
    __syncthreads();
    __shared__ float mb, rb;
    if (t == 0) {
        float S1 = ps[0] + ps[1] + ps[2] + ps[3];
        float S2 = ps2[0] + ps2[1] + ps2[2] + ps2[3];
        float m  = S1 * (1.0f / DIM);
        float var = S2 * (1.0f / DIM) - m * m;
        mb = m;
        rb = rsqrtf(var + 1e-5f);
    }
    __syncthreads();
    float r = (v - mb) * rb * w[t] + bvec[t];
    if (addend) r += addend[(size_t)token * DIM + t];
    out[(size_t)token * DIM + t] = r;
}

// ---------------------------------------------------------------------------
// Simple tiled fp32 GEMM: C[M,N] = (res? res : 0) + A[M,K] @ B[K,N] + bias[N]
// optional relu. BM=BN=64, BK=16, 256 threads, 4x4 micro-tile per thread.
// M % 64 == 0, N % 64 == 0, K % 16 == 0 (all true for our shapes).
// ---------------------------------------------------------------------------
#define BM 64
#define BN 64
#define BK 16

__global__ __launch_bounds__(256) void sgemm_kernel(
    const float* __restrict__ A, const float* __restrict__ Bm,
    const float* __restrict__ bias, const float* __restrict__ res,
    float* __restrict__ C, int M, int N, int K, int do_relu)
{
    __shared__ float As[BK][BM + 1];
    __shared__ float Bs[BK][BN + 1];

    int bx = blockIdx.x;   // N tile
    int by = blockIdx.y;   // M tile
    int tid = threadIdx.x;
    int tx = tid & 15;
    int ty = tid >> 4;

    int row0 = by * BM + ty * 4;
    int col0 = bx * BN + tx * 4;

    float acc[4][4] = {};

    for (int k0 = 0; k0 < K; k0 += BK) {
        #pragma unroll
        for (int i = 0; i < 4; i++) {
            int idx = tid + i * 256;        // 0..1023
            int r = idx / BK;               // 0..63
            int c = idx % BK;               // 0..15
            As[c][r] = A[(size_t)(by * BM + r) * K + k0 + c];
        }
        #pragma unroll
        for (int i = 0; i < 4; i++) {
            int idx = tid + i * 256;
            int r = idx / BN;               // 0..15
            int c = idx % BN;               // 0..63
            Bs[r][c] = Bm[(size_t)(k0 + r) * N + bx * BN + c];
        }
        __syncthreads();
        #pragma unroll
        for (int kk = 0; kk < BK; kk++) {
            float a[4], b[4];
            #pragma unroll
            for (int i = 0; i < 4; i++) a[i] = As[kk][ty * 4 + i];
            #pragma unroll
            for (int j = 0; j < 4; j++) b[j] = Bs[kk][tx * 4 + j];
            #pragma unroll
            for (int i = 0; i < 4; i++)
                #pragma unroll
                for (int j = 0; j < 4; j++)
                    acc[i][j] = fmaf(a[i], b[j], acc[i][j]);
        }
        __syncthreads();
    }

    #pragma unroll
    for (int i = 0; i < 4; i++) {
        int r = row0 + i;
        #pragma unroll
        for (int j = 0; j < 4; j++) {
            int c = col0 + j;
            float v = acc[i][j] + bias[c];
            if (res) v += res[(size_t)r * N + c];
            if (do_relu) v = fmaxf(v, 0.0f);
            C[(size_t)r * N + c] = v;
        }
    }
}

// ---------------------------------------------------------------------------
// MS-deformable attention sampling. One block per token, 256 threads:
// thread = (head h = t>>5, channel d = t&31). Softmax over 16 (l,p) per head,
// bilinear-gather 4 corners from value, weighted-accumulate 32 channels.
// ---------------------------------------------------------------------------
__global__ __launch_bounds__(256) void msdeform_kernel(
    const float* __restrict__ value,     // (B, SEQ, NHEAD, HDIM)
    const float* __restrict__ off_buf,   // (MTOK, 256)
    const float* __restrict__ attn_buf,  // (MTOK, 128)
    const float* __restrict__ ref,       // (B, SEQ, NLVL, 2)
    float* __restrict__ samp_out)        // (MTOK, 256)
{
    const int Hs[NLVL] = {64, 32, 16, 8};
    const int Ws[NLVL] = {64, 32, 16, 8};
    const int St[NLVL] = {0, 4096, 5120, 5376};

    int token = blockIdx.x;
    int b = token / SEQ;
    int t = threadIdx.x;
    int h = t >> 5;
    int d = t & 31;

    __shared__ float s_attn[NHEAD][16];
    __shared__ float s_off[NHEAD][16][2];
    __shared__ float s_ref[NLVL][2];

    if (t < 128) {
        int hh = t >> 4, i = t & 15;
        s_attn[hh][i]  = attn_buf[(size_t)token * 128 + t];
        s_off[hh][i][0] = off_buf[(size_t)token * 256 + t * 2];
        s_off[hh][i][1] = off_buf[(size_t)token * 256 + t * 2 + 1];
    }
    if (t < 8) s_ref[t >> 1][t & 1] = ref[(size_t)token * 8 + t];
    __syncthreads();

    if (t < NHEAD) {
        float mx = -1e30f;
        #pragma unroll
        for (int i = 0; i < 16; i++) mx = fmaxf(mx, s_attn[t][i]);
        float sum = 0.0f;
        #pragma unroll
        for (int i = 0; i < 16; i++) {
            float e = __expf(s_attn[t][i] - mx);
            s_attn[t][i] = e;
            sum += e;
        }
        float inv = 1.0f / sum;
        #pragma unroll
        for (int i = 0; i < 16; i++) s_attn[t][i] *= inv;
    }
    __syncthreads();

    const size_t vbase = ((size_t)b * SEQ) * (NHEAD * HDIM) + h * HDIM + d;

    float acc = 0.0f;
    #pragma unroll
    for (int l = 0; l < NLVL; l++) {
        const int H = Hs[l], W = Ws[l], s0 = St[l];
        const float fH = (float)H, fW = (float)W;
        const float rx = s_ref[l][0], ry = s_ref[l][1];
        #pragma unroll
        for (int p = 0; p < NPT; p++) {
            int i = l * 4 + p;
            float aw = s_attn[h][i];
            float lx = rx + s_off[h][i][0] / fW;
            float ly = ry + s_off[h][i][1] / fH;
            float x = lx * fW - 0.5f;
            float y = ly * fH - 0.5f;
            float x0f = floorf(x), y0f = floorf(y);
            float wx1 = x - x0f, wy1 = y - y0f;
            float wx0 = 1.0f - wx1, wy0 = 1.0f - wy1;
            int x0 = (int)x0f, y0 = (int)y0f;

            float sv = 0.0f;
            #pragma unroll
            for (int cy = 0; cy < 2; cy++) {
                int yi = y0 + cy;
                float wy = cy ? wy1 : wy0;
                bool vy = (yi >= 0) && (yi < H);
                int yc = min(max(yi, 0), H - 1);
                #pragma unroll
                for (int cx = 0; cx < 2; cx++) {
                    int xi = x0 + cx;
                    float wx = cx ? wx1 : wx0;
                    bool vx = (xi >= 0) && (xi < W);
                    int xc = min(max(xi, 0), W - 1);
                    float v = value[vbase + (size_t)(s0 + yc * W + xc) * (NHEAD * HDIM)];
                    sv += ((vx && vy) ? v : 0.0f) * (wx * wy);
                }
            }
            acc = fmaf(aw, sv, acc);
        }
    }
    samp_out[(size_t)token * DIM + h * HDIM + d] = acc;
}

// ---------------------------------------------------------------------------
// Launch
// ---------------------------------------------------------------------------
extern "C" void kernel_launch(void* const* d_in, const int* in_sizes, int n_in,
                              void* d_out, int out_size, void* d_ws, size_t ws_size,
                              hipStream_t stream) {
    const float* input = (const float*)d_in[0];
    const float* pos   = (const float*)d_in[1];
    const float* ref   = (const float*)d_in[2];
    // d_in[3] shape, d_in[4] level_start: compile-time constants
    const float* ln1_w = (const float*)d_in[5];
    const float* ln1_b = (const float*)d_in[6];
    const float* W_off = (const float*)d_in[7];
    const float* b_off = (const float*)d_in[8];
    const float* W_attn = (const float*)d_in[9];
    const float* b_attn = (const float*)d_in[10];
    const float* W_val = (const float*)d_in[11];
    const float* b_val = (const float*)d_in[12];
    const float* W_out = (const float*)d_in[13];
    const float* b_out = (const float*)d_in[14];
    const float* ln2_w = (const float*)d_in[15];
    const float* ln2_b = (const float*)d_in[16];
    const float* ff_w1 = (const float*)d_in[17];
    const float* ff_b1 = (const float*)d_in[18];
    const float* ff_w2 = (const float*)d_in[19];
    const float* ff_b2 = (const float*)d_in[20];
    float* out = (float*)d_out;

    const size_t M = MTOK;
    float* ws = (float*)d_ws;
    // Buffer layout (floats), with reuse:
    float* q_buf    = ws;                    // M*256  (later: samp_buf)
    float* samp_buf = ws;                    //   reuses q
    float* val_buf  = ws + M * 256;          // M*256  (later: x_buf)
    float* x_buf    = ws + M * 256;          //   reuses value
    float* off_buf  = ws + 2 * M * 256;      // M*256  (later: y_buf)
    float* y_buf    = ws + 2 * M * 256;      //   reuses off
    float* attn_buf = ws + 3 * M * 256;      // M*128  (overlapped by h later)
    float* h_buf    = ws + 3 * M * 256;      // M*1024 (attn dead by then)
    // Peak: 3*M*256 + M*1024 = M*1792 floats ≈ 156 MB

    dim3 blk(256);

    // 1) q = LN1(input) + pos
    ln_kernel<<<dim3(M), blk, 0, stream>>>(input, ln1_w, ln1_b, pos, q_buf);

    // 2) value = input @ W_val + b_val
    sgemm_kernel<<<dim3(DIM / BN, M / BM), blk, 0, stream>>>(
        input, W_val, b_val, nullptr, val_buf, M, DIM, DIM, 0);

    // 3) off = q @ W_off + b_off
    sgemm_kernel<<<dim3(DIM / BN, M / BM), blk, 0, stream>>>(
        q_buf, W_off, b_off, nullptr, off_buf, M, DIM, DIM, 0);

    // 4) attn_logits = q @ W_attn + b_attn
    sgemm_kernel<<<dim3(128 / BN, M / BM), blk, 0, stream>>>(
        q_buf, W_attn, b_attn, nullptr, attn_buf, M, 128, DIM, 0);

    // 5) deformable sampling -> samp (reuses q region; q only read via LDS-free
    //    GEMMs already done)
    msdeform_kernel<<<dim3(M), blk, 0, stream>>>(
        val_buf, off_buf, attn_buf, ref, samp_buf);

    // 6) x = input + samp @ W_out + b_out
    sgemm_kernel<<<dim3(DIM / BN, M / BM), blk, 0, stream>>>(
        samp_buf, W_out, b_out, input, x_buf, M, DIM, DIM, 0);

    // 7) y = LN2(x)
    ln_kernel<<<dim3(M), blk, 0, stream>>>(x_buf, ln2_w, ln2_b, nullptr, y_buf);

    // 8) h = relu(y @ ff_w1 + ff_b1)
    sgemm_kernel<<<dim3(FFDIM / BN, M / BM), blk, 0, stream>>>(
        y_buf, ff_w1, ff_b1, nullptr, h_buf, M, FFDIM, DIM, 1);

    // 9) out = x + h @ ff_w2 + ff_b2
    sgemm_kernel<<<dim3(DIM / BN, M / BM), blk, 0, stream>>>(
        h_buf, ff_w2, ff_b2, x_buf, out, M, DIM, FFDIM, 0);
}

// Round 2
// 417.178 us; speedup vs baseline: 2.3607x; 2.3607x over previous
//
#include <hip/hip_runtime.h>
#include <math.h>

#define DIM 256
#define NHEAD 8
#define NLVL 4
#define NPT 4
#define HDIM 32
#define FFDIM 1024
#define BATCH 4
#define SEQ 5440
#define MTOK (BATCH * SEQ)   // 21760

typedef __attribute__((ext_vector_type(8))) short short8;
typedef __attribute__((ext_vector_type(4))) float f32x4;

__device__ __forceinline__ unsigned short f2bf(float f) {
    union { float f; unsigned int u; } x; x.f = f;
    unsigned int r = x.u + 0x7fffu + ((x.u >> 16) & 1u);
    return (unsigned short)(r >> 16);
}
__device__ __forceinline__ float bf2f(unsigned short b) {
    union { unsigned int u; float f; } x; x.u = ((unsigned int)b) << 16;
    return x.f;
}

// ---------------------------------------------------------------------------
// fp32 -> bf16 elementwise (n % 4 == 0)
// ---------------------------------------------------------------------------
__global__ __launch_bounds__(256) void cvt_bf16_kernel(
    const float* __restrict__ in, unsigned short* __restrict__ out, int n)
{
    int i = (blockIdx.x * 256 + threadIdx.x) * 4;
    if (i >= n) return;
    float4 v = *(const float4*)(in + i);
    ushort4 o;
    o.x = f2bf(v.x); o.y = f2bf(v.y); o.z = f2bf(v.z); o.w = f2bf(v.w);
    *(ushort4*)(out + i) = o;
}

// ---------------------------------------------------------------------------
// Weight transpose + convert: Wt[n*K + k] = bf16(W[k*N + n])
// ---------------------------------------------------------------------------
__global__ __launch_bounds__(256) void wt_bf16_kernel(
    const float* __restrict__ W, unsigned short* __restrict__ Wt, int K, int N)
{
    int idx = blockIdx.x * 256 + threadIdx.x;
    if (idx >= N * K) return;
    int k = idx % K;
    int n = idx / K;
    Wt[idx] = f2bf(W[(size_t)k * N + n]);
}

// ---------------------------------------------------------------------------
// LayerNorm (+ optional addend), bf16 or fp32 output. One block per token.
// ---------------------------------------------------------------------------
template<int OUT_BF16>
__global__ __launch_bounds__(256) void ln_kernel(
    const float* __restrict__ x, const float* __restrict__ w,
    const float* __restrict__ bvec, const float* __restrict__ addend,
    void* __restrict__ out)
{
    int token = blockIdx.x;
    int t = threadIdx.x;
    float v = x[(size_t)token * DIM + t];

    float s = v, s2 = v * v;
    #pragma unroll
    for (int o = 32; o > 0; o >>= 1) {
        s  += __shfl_down(s, o);
        s2 += __shfl_down(s2, o);
    }
    __shared__ float ps[4], ps2[4];
    int wid = t >> 6, lane = t & 63;
    if (lane == 0) { ps[wid] = s; ps2[wid] = s2; }
    __syncthreads();
    __shared__ float mb, rb;
    if (t == 0) {
        float S1 = ps[0] + ps[1] + ps[2] + ps[3];
        float S2 = ps2[0] + ps2[1] + ps2[2] + ps2[3];
        float m  = S1 * (1.0f / DIM);
        float var = S2 * (1.0f / DIM) - m * m;
        mb = m;
        rb = rsqrtf(var + 1e-5f);
    }
    __syncthreads();
    float r = (v - mb) * rb * w[t] + bvec[t];
    if (addend) r += addend[(size_t)token * DIM + t];
    if (OUT_BF16)
        ((unsigned short*)out)[(size_t)token * DIM + t] = f2bf(r);
    else
        ((float*)out)[(size_t)token * DIM + t] = r;
}

// ---------------------------------------------------------------------------
// bf16 MFMA GEMM: C[M,N] = A[M,K](bf16) @ Bt[N,K](bf16)^T + bias (+res)(relu)
// Tile 128x128, BK=32, 256 threads = 4 waves, each wave a 64x64 quadrant
// (4x4 tiles of 16x16x32 MFMA). LDS stride padded to 40 bf16 (2-way only).
// Requires: M%128==0, N%128==0, K%32==0.
// ---------------------------------------------------------------------------
#define LDSTR 40

template<int OUT_BF16, int RELU, int HAS_RES>
__global__ __launch_bounds__(256) void mfma_gemm(
    const unsigned short* __restrict__ A,
    const unsigned short* __restrict__ Bt,
    const float* __restrict__ bias,
    const float* __restrict__ res,
    void* __restrict__ Cout,
    int M, int N, int K)
{
    __shared__ __align__(16) unsigned short As[128 * LDSTR];
    __shared__ __align__(16) unsigned short Bs[128 * LDSTR];

    const int tid  = threadIdx.x;
    const int lane = tid & 63;
    const int wv   = tid >> 6;      // 0..3
    const int wr   = wv >> 1;       // wave row quadrant
    const int wc   = wv & 1;        // wave col quadrant
    const int m16  = lane & 15;
    const int quad = lane >> 4;     // 0..3

    const int bm0 = blockIdx.y * 128;
    const int bn0 = blockIdx.x * 128;

    // staging indices: thread t loads rows (t>>2)+{0,64}, 8 bf16 at col (t&3)*8
    const int srow = tid >> 2;
    const int scol = (tid & 3) * 8;

    f32x4 acc[4][4] = {};

    for (int k0 = 0; k0 < K; k0 += 32) {
        uint4 av0 = *(const uint4*)(A  + (size_t)(bm0 + srow)      * K + k0 + scol);
        uint4 av1 = *(const uint4*)(A  + (size_t)(bm0 + srow + 64) * K + k0 + scol);
        uint4 bv0 = *(const uint4*)(Bt + (size_t)(bn0 + srow)      * K + k0 + scol);
        uint4 bv1 = *(const uint4*)(Bt + (size_t)(bn0 + srow + 64) * K + k0 + scol);
        if (k0) __syncthreads();
        *(uint4*)&As[(srow)      * LDSTR + scol] = av0;
        *(uint4*)&As[(srow + 64) * LDSTR + scol] = av1;
        *(uint4*)&Bs[(srow)      * LDSTR + scol] = bv0;
        *(uint4*)&Bs[(srow + 64) * LDSTR + scol] = bv1;
        __syncthreads();

        short8 af[4], bf[4];
        #pragma unroll
        for (int i = 0; i < 4; i++)
            af[i] = *(const short8*)&As[(wr * 64 + i * 16 + m16) * LDSTR + quad * 8];
        #pragma unroll
        for (int j = 0; j < 4; j++)
            bf[j] = *(const short8*)&Bs[(wc * 64 + j * 16 + m16) * LDSTR + quad * 8];

        #pragma unroll
        for (int i = 0; i < 4; i++)
            #pragma unroll
            for (int j = 0; j < 4; j++)
                acc[i][j] = __builtin_amdgcn_mfma_f32_16x16x32_bf16(
                    af[i], bf[j], acc[i][j], 0, 0, 0);
    }

    // Epilogue: D mapping col = lane&15, row = quad*4 + r (m89-verified)
    #pragma unroll
    for (int i = 0; i < 4; i++) {
        #pragma unroll
        for (int j = 0; j < 4; j++) {
            int colb = bn0 + wc * 64 + j * 16 + m16;
            float bcol = bias[colb];
            #pragma unroll
            for (int r = 0; r < 4; r++) {
                int rowb = bm0 + wr * 64 + i * 16 + quad * 4 + r;
                float v = acc[i][j][r] + bcol;
                if (HAS_RES) v += res[(size_t)rowb * N + colb];
                if (RELU) v = fmaxf(v, 0.0f);
                if (OUT_BF16)
                    ((unsigned short*)Cout)[(size_t)rowb * N + colb] = f2bf(v);
                else
                    ((float*)Cout)[(size_t)rowb * N + colb] = v;
            }
        }
    }
}

// ---------------------------------------------------------------------------
// MS-deformable attention sampling. One block per token, 256 threads.
// value is bf16 now; samp output bf16.
// ---------------------------------------------------------------------------
__global__ __launch_bounds__(256) void msdeform_kernel(
    const unsigned short* __restrict__ value,  // (B, SEQ, NHEAD, HDIM) bf16
    const float* __restrict__ off_buf,         // (MTOK, 256) fp32
    const float* __restrict__ attn_buf,        // (MTOK, 128) fp32
    const float* __restrict__ ref,             // (B, SEQ, NLVL, 2)
    unsigned short* __restrict__ samp_out)     // (MTOK, 256) bf16
{
    const int Hs[NLVL] = {64, 32, 16, 8};
    const int Ws[NLVL] = {64, 32, 16, 8};
    const int St[NLVL] = {0, 4096, 5120, 5376};

    int token = blockIdx.x;
    int b = token / SEQ;
    int t = threadIdx.x;
    int h = t >> 5;
    int d = t & 31;

    __shared__ float s_attn[NHEAD][16];
    __shared__ float s_off[NHEAD][16][2];
    __shared__ float s_ref[NLVL][2];

    if (t < 128) {
        int hh = t >> 4, i = t & 15;
        s_attn[hh][i]  = attn_buf[(size_t)token * 128 + t];
        s_off[hh][i][0] = off_buf[(size_t)token * 256 + t * 2];
        s_off[hh][i][1] = off_buf[(size_t)token * 256 + t * 2 + 1];
    }
    if (t < 8) s_ref[t >> 1][t & 1] = ref[(size_t)token * 8 + t];
    __syncthreads();

    if (t < NHEAD) {
        float mx = -1e30f;
        #pragma unroll
        for (int i = 0; i < 16; i++) mx = fmaxf(mx, s_attn[t][i]);
        float sum = 0.0f;
        #pragma unroll
        for (int i = 0; i < 16; i++) {
            float e = __expf(s_attn[t][i] - mx);
            s_attn[t][i] = e;
            sum += e;
        }
        float inv = 1.0f / sum;
        #pragma unroll
        for (int i = 0; i < 16; i++) s_attn[t][i] *= inv;
    }
    __syncthreads();

    const size_t vbase = ((size_t)b * SEQ) * (NHEAD * HDIM) + h * HDIM + d;

    float acc = 0.0f;
    #pragma unroll
    for (int l = 0; l < NLVL; l++) {
        const int H = Hs[l], W = Ws[l], s0 = St[l];
        const float fH = (float)H, fW = (float)W;
        const float rx = s_ref[l][0], ry = s_ref[l][1];
        #pragma unroll
        for (int p = 0; p < NPT; p++) {
            int i = l * 4 + p;
            float aw = s_attn[h][i];
            float lx = rx + s_off[h][i][0] / fW;
            float ly = ry + s_off[h][i][1] / fH;
            float x = lx * fW - 0.5f;
            float y = ly * fH - 0.5f;
            float x0f = floorf(x), y0f = floorf(y);
            float wx1 = x - x0f, wy1 = y - y0f;
            float wx0 = 1.0f - wx1, wy0 = 1.0f - wy1;
            int x0 = (int)x0f, y0 = (int)y0f;

            float sv = 0.0f;
            #pragma unroll
            for (int cy = 0; cy < 2; cy++) {
                int yi = y0 + cy;
                float wy = cy ? wy1 : wy0;
                bool vy = (yi >= 0) && (yi < H);
                int yc = min(max(yi, 0), H - 1);
                #pragma unroll
                for (int cx = 0; cx < 2; cx++) {
                    int xi = x0 + cx;
                    float wx = cx ? wx1 : wx0;
                    bool vx = (xi >= 0) && (xi < W);
                    int xc = min(max(xi, 0), W - 1);
                    float v = bf2f(value[vbase + (size_t)(s0 + yc * W + xc) * (NHEAD * HDIM)]);
                    sv += ((vx && vy) ? v : 0.0f) * (wx * wy);
                }
            }
            acc = fmaf(aw, sv, acc);
        }
    }
    samp_out[(size_t)token * DIM + h * HDIM + d] = f2bf(acc);
}

// ---------------------------------------------------------------------------
// Launch
// ---------------------------------------------------------------------------
extern "C" void kernel_launch(void* const* d_in, const int* in_sizes, int n_in,
                              void* d_out, int out_size, void* d_ws, size_t ws_size,
                              hipStream_t stream) {
    const float* input = (const float*)d_in[0];
    const float* pos   = (const float*)d_in[1];
    const float* ref   = (const float*)d_in[2];
    const float* ln1_w = (const float*)d_in[5];
    const float* ln1_b = (const float*)d_in[6];
    const float* W_off = (const float*)d_in[7];
    const float* b_off = (const float*)d_in[8];
    const float* W_attn = (const float*)d_in[9];
    const float* b_attn = (const float*)d_in[10];
    const float* W_val = (const float*)d_in[11];
    const float* b_val = (const float*)d_in[12];
    const float* W_out = (const float*)d_in[13];
    const float* b_out = (const float*)d_in[14];
    const float* ln2_w = (const float*)d_in[15];
    const float* ln2_b = (const float*)d_in[16];
    const float* ff_w1 = (const float*)d_in[17];
    const float* ff_b1 = (const float*)d_in[18];
    const float* ff_w2 = (const float*)d_in[19];
    const float* ff_b2 = (const float*)d_in[20];
    float* out = (float*)d_out;

    const size_t M = MTOK;
    float* ws = (float*)d_ws;

    // Workspace layout (float units), with reuse:
    unsigned short* input_bf = (unsigned short*)(ws);                  // M*128f
    unsigned short* y_bf     = input_bf;                               // reuse
    unsigned short* q_bf     = (unsigned short*)(ws + M * 128);        // M*128f
    unsigned short* samp_bf  = q_bf;                                   // reuse
    float*  off_buf  = ws + M * 256;                                   // M*256f
    float*  x_buf    = off_buf;                                        // reuse
    float*  attn_buf = ws + M * 512;                                   // M*128f
    unsigned short* val_bf   = (unsigned short*)(ws + M * 640);        // M*128f
    unsigned short* h_bf     = (unsigned short*)(ws + M * 512);        // M*512f (after attn/val dead)
    unsigned short* wts      = (unsigned short*)(ws + M * 1024);

    unsigned short* wval_t  = wts;                       // 256x256
    unsigned short* woff_t  = wval_t  + 256 * 256;       // 256x256
    unsigned short* wattn_t = woff_t  + 256 * 256;       // 128x256
    unsigned short* wout_t  = wattn_t + 128 * 256;       // 256x256
    unsigned short* ffw1_t  = wout_t  + 256 * 256;       // 1024x256
    unsigned short* ffw2_t  = ffw1_t  + 1024 * 256;      // 256x1024

    dim3 blk(256);

    // 0) conversions
    cvt_bf16_kernel<<<dim3((M * 256 / 4 + 255) / 256), blk, 0, stream>>>(
        input, input_bf, (int)(M * 256));
    wt_bf16_kernel<<<dim3((256 * 256 + 255) / 256), blk, 0, stream>>>(W_val, wval_t, 256, 256);
    wt_bf16_kernel<<<dim3((256 * 256 + 255) / 256), blk, 0, stream>>>(W_off, woff_t, 256, 256);
    wt_bf16_kernel<<<dim3((128 * 256 + 255) / 256), blk, 0, stream>>>(W_attn, wattn_t, 256, 128);
    wt_bf16_kernel<<<dim3((256 * 256 + 255) / 256), blk, 0, stream>>>(W_out, wout_t, 256, 256);
    wt_bf16_kernel<<<dim3((1024 * 256 + 255) / 256), blk, 0, stream>>>(ff_w1, ffw1_t, 256, 1024);
    wt_bf16_kernel<<<dim3((256 * 1024 + 255) / 256), blk, 0, stream>>>(ff_w2, ffw2_t, 1024, 256);

    // 1) q = LN1(input) + pos  (bf16)
    ln_kernel<1><<<dim3(M), blk, 0, stream>>>(input, ln1_w, ln1_b, pos, q_bf);

    // 2) value = input @ W_val + b_val  (bf16)
    mfma_gemm<1,0,0><<<dim3(256/128, M/128), blk, 0, stream>>>(
        input_bf, wval_t, b_val, nullptr, val_bf, M, 256, 256);

    // 3) off = q @ W_off + b_off  (fp32)
    mfma_gemm<0,0,0><<<dim3(256/128, M/128), blk, 0, stream>>>(
        q_bf, woff_t, b_off, nullptr, off_buf, M, 256, 256);

    // 4) attn_logits = q @ W_attn + b_attn  (fp32)
    mfma_gemm<0,0,0><<<dim3(128/128, M/128), blk, 0, stream>>>(
        q_bf, wattn_t, b_attn, nullptr, attn_buf, M, 128, 256);

    // 5) sampling -> samp (bf16, reuses q region)
    msdeform_kernel<<<dim3(M), blk, 0, stream>>>(
        val_bf, off_buf, attn_buf, ref, samp_bf);

    // 6) x = input + samp @ W_out + b_out  (fp32, reuses off region)
    mfma_gemm<0,0,1><<<dim3(256/128, M/128), blk, 0, stream>>>(
        samp_bf, wout_t, b_out, input, x_buf, M, 256, 256);

    // 7) y = LN2(x)  (bf16, reuses input_bf region)
    ln_kernel<1><<<dim3(M), blk, 0, stream>>>(x_buf, ln2_w, ln2_b, nullptr, y_bf);

    // 8) h = relu(y @ ff_w1 + ff_b1)  (bf16)
    mfma_gemm<1,1,0><<<dim3(1024/128, M/128), blk, 0, stream>>>(
        y_bf, ffw1_t, ff_b1, nullptr, h_bf, M, 1024, 256);

    // 9) out = x + h @ ff_w2 + ff_b2  (fp32)
    mfma_gemm<0,0,1><<<dim3(256/128, M/128), blk, 0, stream>>>(
        h_bf, ffw2_t, ff_b2, x_buf, out, M, 256, 1024);
}

// Round 3
// 308.113 us; speedup vs baseline: 3.1964x; 1.3540x over previous
//
#include <hip/hip_runtime.h>
#include <math.h>

#define DIM 256
#define NHEAD 8
#define NLVL 4
#define NPT 4
#define HDIM 32
#define FFDIM 1024
#define BATCH 4
#define SEQ 5440
#define MTOK (BATCH * SEQ)   // 21760

typedef __attribute__((ext_vector_type(8))) short short8;
typedef __attribute__((ext_vector_type(4))) float f32x4;

__device__ __forceinline__ unsigned short f2bf(float f) {
    union { float f; unsigned int u; } x; x.f = f;
    unsigned int r = x.u + 0x7fffu + ((x.u >> 16) & 1u);
    return (unsigned short)(r >> 16);
}
__device__ __forceinline__ float bf_lo(unsigned int u) {
    union { unsigned int u; float f; } x; x.u = u << 16;
    return x.f;
}
__device__ __forceinline__ float bf_hi(unsigned int u) {
    union { unsigned int u; float f; } x; x.u = u & 0xffff0000u;
    return x.f;
}

// ---------------------------------------------------------------------------
// Combined weight transpose+convert for all 6 weight matrices.
// wts layout: [wval 256x256][woff 256x256][wattn 128x256][wout 256x256]
//             [ffw1 1024x256][ffw2 256x1024]   (N-major, K-contig)
// ---------------------------------------------------------------------------
__global__ __launch_bounds__(256) void wtprep_kernel(
    const float* __restrict__ W_val, const float* __restrict__ W_off,
    const float* __restrict__ W_attn, const float* __restrict__ W_out,
    const float* __restrict__ ff_w1, const float* __restrict__ ff_w2,
    unsigned short* __restrict__ wts)
{
    int idx = blockIdx.x * 256 + threadIdx.x;
    const float* W; int K, N, base;
    if      (idx < 65536)  { W = W_val;  K = 256;  N = 256;  base = 0; }
    else if (idx < 131072) { W = W_off;  K = 256;  N = 256;  base = 65536; }
    else if (idx < 163840) { W = W_attn; K = 256;  N = 128;  base = 131072; }
    else if (idx < 229376) { W = W_out;  K = 256;  N = 256;  base = 163840; }
    else if (idx < 491520) { W = ff_w1;  K = 256;  N = 1024; base = 229376; }
    else if (idx < 753664) { W = ff_w2;  K = 1024; N = 256;  base = 491520; }
    else return;
    int li = idx - base;
    int k = li % K;
    int n = li / K;
    wts[idx] = f2bf(W[(size_t)k * N + n]);
}

// ---------------------------------------------------------------------------
// LayerNorm, wave-per-token, float4 per lane, xor-shuffle reduce (no LDS).
// Optionally also emits bf16 copy of the RAW input (for the value GEMM).
// Block = 256 threads = 4 waves = 4 tokens.
// ---------------------------------------------------------------------------
template<int COPY_BF16>
__global__ __launch_bounds__(256) void ln_kernel(
    const float* __restrict__ x, const float* __restrict__ w,
    const float* __restrict__ bvec, const float* __restrict__ addend,
    unsigned short* __restrict__ out, unsigned short* __restrict__ xbf)
{
    int wv = threadIdx.x >> 6, lane = threadIdx.x & 63;
    int token = blockIdx.x * 4 + wv;
    size_t base = (size_t)token * DIM + lane * 4;
    float4 v = *(const float4*)(x + base);
    float s  = v.x + v.y + v.z + v.w;
    float s2 = v.x * v.x + v.y * v.y + v.z * v.z + v.w * v.w;
    #pragma unroll
    for (int o = 1; o < 64; o <<= 1) {
        s  += __shfl_xor(s, o);
        s2 += __shfl_xor(s2, o);
    }
    float m  = s * (1.0f / DIM);
    float rs = rsqrtf(s2 * (1.0f / DIM) - m * m + 1e-5f);
    float4 w4 = *(const float4*)(w + lane * 4);
    float4 b4 = *(const float4*)(bvec + lane * 4);
    float4 r;
    r.x = (v.x - m) * rs * w4.x + b4.x;
    r.y = (v.y - m) * rs * w4.y + b4.y;
    r.z = (v.z - m) * rs * w4.z + b4.z;
    r.w = (v.w - m) * rs * w4.w + b4.w;
    if (addend) {
        float4 a = *(const float4*)(addend + base);
        r.x += a.x; r.y += a.y; r.z += a.z; r.w += a.w;
    }
    ushort4 o4;
    o4.x = f2bf(r.x); o4.y = f2bf(r.y); o4.z = f2bf(r.z); o4.w = f2bf(r.w);
    *(ushort4*)(out + base) = o4;
    if (COPY_BF16) {
        ushort4 c;
        c.x = f2bf(v.x); c.y = f2bf(v.y); c.z = f2bf(v.z); c.w = f2bf(v.w);
        *(ushort4*)(xbf + base) = c;
    }
}

// ---------------------------------------------------------------------------
// bf16 MFMA GEMM: C[M,N] = A[M,K](bf16) @ Bt[N,K](bf16)^T + bias (+res)(relu)
// Tile 128x128, BK=32, 256 threads = 4 waves, each a 64x64 quadrant.
// ---------------------------------------------------------------------------
#define LDSTR 40

template<int OUT_BF16, int RELU, int HAS_RES>
__global__ __launch_bounds__(256) void mfma_gemm(
    const unsigned short* __restrict__ A,
    const unsigned short* __restrict__ Bt,
    const float* __restrict__ bias,
    const float* __restrict__ res,
    void* __restrict__ Cout,
    int M, int N, int K)
{
    __shared__ __align__(16) unsigned short As[128 * LDSTR];
    __shared__ __align__(16) unsigned short Bs[128 * LDSTR];

    const int tid  = threadIdx.x;
    const int lane = tid & 63;
    const int wv   = tid >> 6;
    const int wr   = wv >> 1;
    const int wc   = wv & 1;
    const int m16  = lane & 15;
    const int quad = lane >> 4;

    const int bm0 = blockIdx.y * 128;
    const int bn0 = blockIdx.x * 128;

    const int srow = tid >> 2;
    const int scol = (tid & 3) * 8;

    f32x4 acc[4][4] = {};

    for (int k0 = 0; k0 < K; k0 += 32) {
        uint4 av0 = *(const uint4*)(A  + (size_t)(bm0 + srow)      * K + k0 + scol);
        uint4 av1 = *(const uint4*)(A  + (size_t)(bm0 + srow + 64) * K + k0 + scol);
        uint4 bv0 = *(const uint4*)(Bt + (size_t)(bn0 + srow)      * K + k0 + scol);
        uint4 bv1 = *(const uint4*)(Bt + (size_t)(bn0 + srow + 64) * K + k0 + scol);
        if (k0) __syncthreads();
        *(uint4*)&As[(srow)      * LDSTR + scol] = av0;
        *(uint4*)&As[(srow + 64) * LDSTR + scol] = av1;
        *(uint4*)&Bs[(srow)      * LDSTR + scol] = bv0;
        *(uint4*)&Bs[(srow + 64) * LDSTR + scol] = bv1;
        __syncthreads();

        short8 af[4], bf[4];
        #pragma unroll
        for (int i = 0; i < 4; i++)
            af[i] = *(const short8*)&As[(wr * 64 + i * 16 + m16) * LDSTR + quad * 8];
        #pragma unroll
        for (int j = 0; j < 4; j++)
            bf[j] = *(const short8*)&Bs[(wc * 64 + j * 16 + m16) * LDSTR + quad * 8];

        #pragma unroll
        for (int i = 0; i < 4; i++)
            #pragma unroll
            for (int j = 0; j < 4; j++)
                acc[i][j] = __builtin_amdgcn_mfma_f32_16x16x32_bf16(
                    af[i], bf[j], acc[i][j], 0, 0, 0);
    }

    #pragma unroll
    for (int i = 0; i < 4; i++) {
        #pragma unroll
        for (int j = 0; j < 4; j++) {
            int colb = bn0 + wc * 64 + j * 16 + m16;
            float bcol = bias[colb];
            #pragma unroll
            for (int r = 0; r < 4; r++) {
                int rowb = bm0 + wr * 64 + i * 16 + quad * 4 + r;
                float v = acc[i][j][r] + bcol;
                if (HAS_RES) v += res[(size_t)rowb * N + colb];
                if (RELU) v = fmaxf(v, 0.0f);
                if (OUT_BF16)
                    ((unsigned short*)Cout)[(size_t)rowb * N + colb] = f2bf(v);
                else
                    ((float*)Cout)[(size_t)rowb * N + colb] = v;
            }
        }
    }
}

// ---------------------------------------------------------------------------
// MS-deformable sampling, channel-vectorized.
// Block = 256 threads = 8 tokens. Thread: tt = t>>5 (token), h = (t>>2)&7,
// dg = t&3 (8 channels each, AND level l = dg since NP=4 points/level).
// Each corner = one uint4 (8 bf16 channels) load.
// ---------------------------------------------------------------------------
__global__ __launch_bounds__(256) void msdeform_kernel(
    const unsigned short* __restrict__ value,  // (B, SEQ, 256) bf16
    const float* __restrict__ off_buf,         // (MTOK, 256)
    const float* __restrict__ attn_buf,        // (MTOK, 128)
    const float* __restrict__ ref,             // (B, SEQ, NLVL, 2)
    unsigned short* __restrict__ samp_out)     // (MTOK, 256) bf16
{
    const int Hs[NLVL] = {64, 32, 16, 8};
    const int Ws[NLVL] = {64, 32, 16, 8};
    const int St[NLVL] = {0, 4096, 5120, 5376};

    const int t  = threadIdx.x;
    const int tt = t >> 5;
    const int h  = (t >> 2) & 7;
    const int dg = t & 3;
    const int token = blockIdx.x * 8 + tt;
    const int b = token / SEQ;

    __shared__ float s_attn[8][NHEAD][16];
    __shared__ float s_loc[8][NHEAD][16][2];

    // attn logits: 4 per thread (level dg's points)
    float4 a4 = *(const float4*)(attn_buf + (size_t)token * 128 + h * 16 + dg * 4);
    *(float4*)&s_attn[tt][h][dg * 4] = a4;

    // offsets for level dg: 4 points x (x,y) = 8 floats
    const float* offp = off_buf + (size_t)token * 256 + h * 32 + dg * 8;
    float4 o0 = *(const float4*)(offp);
    float4 o1 = *(const float4*)(offp + 4);
    float fWd = (float)Ws[dg], fHd = (float)Hs[dg];
    float rx = ref[(size_t)token * 8 + dg * 2 + 0];
    float ry = ref[(size_t)token * 8 + dg * 2 + 1];
    s_loc[tt][h][dg * 4 + 0][0] = rx + o0.x / fWd;
    s_loc[tt][h][dg * 4 + 0][1] = ry + o0.y / fHd;
    s_loc[tt][h][dg * 4 + 1][0] = rx + o0.z / fWd;
    s_loc[tt][h][dg * 4 + 1][1] = ry + o0.w / fHd;
    s_loc[tt][h][dg * 4 + 2][0] = rx + o1.x / fWd;
    s_loc[tt][h][dg * 4 + 2][1] = ry + o1.y / fHd;
    s_loc[tt][h][dg * 4 + 3][0] = rx + o1.z / fWd;
    s_loc[tt][h][dg * 4 + 3][1] = ry + o1.w / fHd;
    __syncthreads();

    if (dg == 0) {
        float mx = -1e30f;
        #pragma unroll
        for (int i = 0; i < 16; i++) mx = fmaxf(mx, s_attn[tt][h][i]);
        float sum = 0.0f;
        #pragma unroll
        for (int i = 0; i < 16; i++) {
            float e = __expf(s_attn[tt][h][i] - mx);
            s_attn[tt][h][i] = e;
            sum += e;
        }
        float inv = 1.0f / sum;
        #pragma unroll
        for (int i = 0; i < 16; i++) s_attn[tt][h][i] *= inv;
    }
    __syncthreads();

    const size_t vbase = ((size_t)b * SEQ) * DIM + h * HDIM + dg * 8;

    float acc[8] = {};
    #pragma unroll
    for (int l = 0; l < NLVL; l++) {
        const int Hl = Hs[l], Wl = Ws[l], s0 = St[l];
        const float fW = (float)Wl, fH = (float)Hl;
        #pragma unroll
        for (int p = 0; p < NPT; p++) {
            int i = l * 4 + p;
            float aw = s_attn[tt][h][i];
            float x = s_loc[tt][h][i][0] * fW - 0.5f;
            float y = s_loc[tt][h][i][1] * fH - 0.5f;
            float x0f = floorf(x), y0f = floorf(y);
            float wx1 = x - x0f, wy1 = y - y0f;
            float wx0 = 1.0f - wx1, wy0 = 1.0f - wy1;
            int x0 = (int)x0f, y0 = (int)y0f;
            #pragma unroll
            for (int cy = 0; cy < 2; cy++) {
                int yi = y0 + cy;
                bool vy = (yi >= 0) && (yi < Hl);
                int yc = min(max(yi, 0), Hl - 1);
                float wy = cy ? wy1 : wy0;
                #pragma unroll
                for (int cx = 0; cx < 2; cx++) {
                    int xi = x0 + cx;
                    bool vx = (xi >= 0) && (xi < Wl);
                    int xc = min(max(xi, 0), Wl - 1);
                    float cw = aw * wy * (cx ? wx1 : wx0) * ((vx && vy) ? 1.0f : 0.0f);
                    uint4 v = *(const uint4*)(value + vbase + (size_t)(s0 + yc * Wl + xc) * DIM);
                    acc[0] = fmaf(cw, bf_lo(v.x), acc[0]);
                    acc[1] = fmaf(cw, bf_hi(v.x), acc[1]);
                    acc[2] = fmaf(cw, bf_lo(v.y), acc[2]);
                    acc[3] = fmaf(cw, bf_hi(v.y), acc[3]);
                    acc[4] = fmaf(cw, bf_lo(v.z), acc[4]);
                    acc[5] = fmaf(cw, bf_hi(v.z), acc[5]);
                    acc[6] = fmaf(cw, bf_lo(v.w), acc[6]);
                    acc[7] = fmaf(cw, bf_hi(v.w), acc[7]);
                }
            }
        }
    }

    uint4 o;
    o.x = (unsigned int)f2bf(acc[0]) | ((unsigned int)f2bf(acc[1]) << 16);
    o.y = (unsigned int)f2bf(acc[2]) | ((unsigned int)f2bf(acc[3]) << 16);
    o.z = (unsigned int)f2bf(acc[4]) | ((unsigned int)f2bf(acc[5]) << 16);
    o.w = (unsigned int)f2bf(acc[6]) | ((unsigned int)f2bf(acc[7]) << 16);
    *(uint4*)(samp_out + (size_t)token * DIM + h * HDIM + dg * 8) = o;
}

// ---------------------------------------------------------------------------
// Launch
// ---------------------------------------------------------------------------
extern "C" void kernel_launch(void* const* d_in, const int* in_sizes, int n_in,
                              void* d_out, int out_size, void* d_ws, size_t ws_size,
                              hipStream_t stream) {
    const float* input = (const float*)d_in[0];
    const float* pos   = (const float*)d_in[1];
    const float* ref   = (const float*)d_in[2];
    const float* ln1_w = (const float*)d_in[5];
    const float* ln1_b = (const float*)d_in[6];
    const float* W_off = (const float*)d_in[7];
    const float* b_off = (const float*)d_in[8];
    const float* W_attn = (const float*)d_in[9];
    const float* b_attn = (const float*)d_in[10];
    const float* W_val = (const float*)d_in[11];
    const float* b_val = (const float*)d_in[12];
    const float* W_out = (const float*)d_in[13];
    const float* b_out = (const float*)d_in[14];
    const float* ln2_w = (const float*)d_in[15];
    const float* ln2_b = (const float*)d_in[16];
    const float* ff_w1 = (const float*)d_in[17];
    const float* ff_b1 = (const float*)d_in[18];
    const float* ff_w2 = (const float*)d_in[19];
    const float* ff_b2 = (const float*)d_in[20];
    float* out = (float*)d_out;

    const size_t M = MTOK;
    float* ws = (float*)d_ws;

    // Workspace layout (float units), with reuse:
    unsigned short* input_bf = (unsigned short*)(ws);                  // M*128f
    unsigned short* y_bf     = input_bf;                               // reuse (input_bf dead after value GEMM)
    unsigned short* q_bf     = (unsigned short*)(ws + M * 128);        // M*128f
    unsigned short* samp_bf  = q_bf;                                   // reuse (q dead after off/attn GEMMs)
    float*  off_buf  = ws + M * 256;                                   // M*256f
    float*  x_buf    = off_buf;                                        // reuse (off dead after msdeform)
    float*  attn_buf = ws + M * 512;                                   // M*128f
    unsigned short* val_bf   = (unsigned short*)(ws + M * 640);        // M*128f
    unsigned short* h_bf     = (unsigned short*)(ws + M * 512);        // M*512f (attn/val dead by then)
    unsigned short* wts      = (unsigned short*)(ws + M * 1024);

    unsigned short* wval_t  = wts;                       // 256x256
    unsigned short* woff_t  = wval_t  + 256 * 256;
    unsigned short* wattn_t = woff_t  + 256 * 256;
    unsigned short* wout_t  = wattn_t + 128 * 256;
    unsigned short* ffw1_t  = wout_t  + 256 * 256;
    unsigned short* ffw2_t  = ffw1_t  + 1024 * 256;

    dim3 blk(256);

    // 0) all weight transposes/conversions in one launch
    wtprep_kernel<<<dim3((753664 + 255) / 256), blk, 0, stream>>>(
        W_val, W_off, W_attn, W_out, ff_w1, ff_w2, wts);

    // 1) q = LN1(input) + pos (bf16)  AND input_bf = bf16(input)
    ln_kernel<1><<<dim3(M / 4), blk, 0, stream>>>(
        input, ln1_w, ln1_b, pos, q_bf, input_bf);

    // 2) value = input @ W_val + b_val  (bf16)
    mfma_gemm<1,0,0><<<dim3(256/128, M/128), blk, 0, stream>>>(
        input_bf, wval_t, b_val, nullptr, val_bf, M, 256, 256);

    // 3) off = q @ W_off + b_off  (fp32)
    mfma_gemm<0,0,0><<<dim3(256/128, M/128), blk, 0, stream>>>(
        q_bf, woff_t, b_off, nullptr, off_buf, M, 256, 256);

    // 4) attn_logits = q @ W_attn + b_attn  (fp32)
    mfma_gemm<0,0,0><<<dim3(128/128, M/128), blk, 0, stream>>>(
        q_bf, wattn_t, b_attn, nullptr, attn_buf, M, 128, 256);

    // 5) sampling -> samp (bf16)
    msdeform_kernel<<<dim3(M / 8), blk, 0, stream>>>(
        val_bf, off_buf, attn_buf, ref, samp_bf);

    // 6) x = input + samp @ W_out + b_out  (fp32)
    mfma_gemm<0,0,1><<<dim3(256/128, M/128), blk, 0, stream>>>(
        samp_bf, wout_t, b_out, input, x_buf, M, 256, 256);

    // 7) y = LN2(x)  (bf16)
    ln_kernel<0><<<dim3(M / 4), blk, 0, stream>>>(
        x_buf, ln2_w, ln2_b, nullptr, y_bf, nullptr);

    // 8) h = relu(y @ ff_w1 + ff_b1)  (bf16)
    mfma_gemm<1,1,0><<<dim3(1024/128, M/128), blk, 0, stream>>>(
        y_bf, ffw1_t, ff_b1, nullptr, h_bf, M, 1024, 256);

    // 9) out = x + h @ ff_w2 + ff_b2  (fp32)
    mfma_gemm<0,0,1><<<dim3(256/128, M/128), blk, 0, stream>>>(
        h_bf, ffw2_t, ff_b2, x_buf, out, M, 256, 1024);
}

// Round 4
// 269.696 us; speedup vs baseline: 3.6517x; 1.1424x over previous
//
#include <hip/hip_runtime.h>
#include <hip/hip_fp16.h>
#include <math.h>

#define DIM 256
#define NHEAD 8
#define NLVL 4
#define NPT 4
#define HDIM 32
#define FFDIM 1024
#define BATCH 4
#define SEQ 5440
#define MTOK (BATCH * SEQ)   // 21760

typedef __attribute__((ext_vector_type(8))) short short8;
typedef __attribute__((ext_vector_type(4))) float f32x4;

__device__ __forceinline__ unsigned short f2bf(float f) {
    union { float f; unsigned int u; } x; x.f = f;
    unsigned int r = x.u + 0x7fffu + ((x.u >> 16) & 1u);
    return (unsigned short)(r >> 16);
}

// async global->LDS, 16 B per lane. LDS dest must be wave-base + lane*16.
__device__ __forceinline__ void gll16(const unsigned short* g, unsigned short* l) {
    __builtin_amdgcn_global_load_lds(
        (const __attribute__((address_space(1))) void*)g,
        (__attribute__((address_space(3))) void*)l,
        16, 0, 0);
}

// ---------------------------------------------------------------------------
// Weight prep: transpose+convert all 6 weights to bf16 N-major/K-contig,
// plus combined off|attn bias vector (384 floats).
// wts layout: [wval 256x256][woff 256x256][wattn 128x256][wout 256x256]
//             [ffw1 1024x256][ffw2 256x1024]
// ---------------------------------------------------------------------------
__global__ __launch_bounds__(256) void wtprep_kernel(
    const float* __restrict__ W_val, const float* __restrict__ W_off,
    const float* __restrict__ W_attn, const float* __restrict__ W_out,
    const float* __restrict__ ff_w1, const float* __restrict__ ff_w2,
    const float* __restrict__ b_off, const float* __restrict__ b_attn,
    unsigned short* __restrict__ wts, float* __restrict__ bcomb)
{
    int idx = blockIdx.x * 256 + threadIdx.x;
    if (blockIdx.x == 0 && threadIdx.x < 384) {
        int li = threadIdx.x;
        bcomb[li] = (li < 256) ? b_off[li] : b_attn[li - 256];
    }
    const float* W; int K, N, base;
    if      (idx < 65536)  { W = W_val;  K = 256;  N = 256;  base = 0; }
    else if (idx < 131072) { W = W_off;  K = 256;  N = 256;  base = 65536; }
    else if (idx < 163840) { W = W_attn; K = 256;  N = 128;  base = 131072; }
    else if (idx < 229376) { W = W_out;  K = 256;  N = 256;  base = 163840; }
    else if (idx < 491520) { W = ff_w1;  K = 256;  N = 1024; base = 229376; }
    else if (idx < 753664) { W = ff_w2;  K = 1024; N = 256;  base = 491520; }
    else return;
    int li = idx - base;
    int k = li % K;
    int n = li / K;
    wts[idx] = f2bf(W[(size_t)k * N + n]);
}

// ---------------------------------------------------------------------------
// LayerNorm, wave-per-token, float4 per lane, xor-shuffle reduce.
// Optionally emits bf16 copy of RAW input. Block = 4 waves = 4 tokens.
// ---------------------------------------------------------------------------
template<int COPY_BF16>
__global__ __launch_bounds__(256) void ln_kernel(
    const float* __restrict__ x, const float* __restrict__ w,
    const float* __restrict__ bvec, const float* __restrict__ addend,
    unsigned short* __restrict__ out, unsigned short* __restrict__ xbf)
{
    int wv = threadIdx.x >> 6, lane = threadIdx.x & 63;
    int token = blockIdx.x * 4 + wv;
    size_t base = (size_t)token * DIM + lane * 4;
    float4 v = *(const float4*)(x + base);
    float s  = v.x + v.y + v.z + v.w;
    float s2 = v.x * v.x + v.y * v.y + v.z * v.z + v.w * v.w;
    #pragma unroll
    for (int o = 1; o < 64; o <<= 1) {
        s  += __shfl_xor(s, o);
        s2 += __shfl_xor(s2, o);
    }
    float m  = s * (1.0f / DIM);
    float rs = rsqrtf(s2 * (1.0f / DIM) - m * m + 1e-5f);
    float4 w4 = *(const float4*)(w + lane * 4);
    float4 b4 = *(const float4*)(bvec + lane * 4);
    float4 r;
    r.x = (v.x - m) * rs * w4.x + b4.x;
    r.y = (v.y - m) * rs * w4.y + b4.y;
    r.z = (v.z - m) * rs * w4.z + b4.z;
    r.w = (v.w - m) * rs * w4.w + b4.w;
    if (addend) {
        float4 a = *(const float4*)(addend + base);
        r.x += a.x; r.y += a.y; r.z += a.z; r.w += a.w;
    }
    ushort4 o4;
    o4.x = f2bf(r.x); o4.y = f2bf(r.y); o4.z = f2bf(r.z); o4.w = f2bf(r.w);
    *(ushort4*)(out + base) = o4;
    if (COPY_BF16) {
        ushort4 c;
        c.x = f2bf(v.x); c.y = f2bf(v.y); c.z = f2bf(v.z); c.w = f2bf(v.w);
        *(ushort4*)(xbf + base) = c;
    }
}

// ---------------------------------------------------------------------------
// bf16 MFMA GEMM, m97-style: global_load_lds staging (16B), 128x128 tile,
// BK=32, 4 waves each a 64x64 quadrant. MFMA args swapped -> acc holds 4
// consecutive COLUMNS per lane -> vectorized epilogue.
// OUT: 0 = fp32, 1 = bf16, 2 = fp16.
// ---------------------------------------------------------------------------
template<int K, int OUT, int RELU, int HAS_RES>
__global__ __launch_bounds__(256) void mfma_gemm(
    const unsigned short* __restrict__ A,
    const unsigned short* __restrict__ Bt,
    const float* __restrict__ bias,
    const float* __restrict__ res,
    void* __restrict__ Cout,
    int M, int N)
{
    __shared__ __align__(16) unsigned short As[128 * 32];
    __shared__ __align__(16) unsigned short Bs[128 * 32];

    const int tid  = threadIdx.x;
    const int lane = tid & 63;
    const int wv   = tid >> 6;
    const int wr   = wv >> 1;
    const int wc   = wv & 1;
    const int m16  = lane & 15;
    const int quad = lane >> 4;

    const int bm0 = blockIdx.y * 128;
    const int bn0 = blockIdx.x * 128;

    // staging slots: element index e = wv*1024 + i*512 + lane*8 (shorts)
    const int e0 = wv * 1024 + lane * 8;
    const int e1 = e0 + 512;
    const int r0 = e0 >> 5, c0 = e0 & 31;
    const int r1 = e1 >> 5, c1 = e1 & 31;

    f32x4 acc[4][4] = {};

    for (int k0 = 0; k0 < K; k0 += 32) {
        if (k0) __syncthreads();
        gll16(A  + (size_t)(bm0 + r0) * K + k0 + c0, As + e0);
        gll16(A  + (size_t)(bm0 + r1) * K + k0 + c1, As + e1);
        gll16(Bt + (size_t)(bn0 + r0) * K + k0 + c0, Bs + e0);
        gll16(Bt + (size_t)(bn0 + r1) * K + k0 + c1, Bs + e1);
        __syncthreads();

        short8 af[4], bf[4];
        #pragma unroll
        for (int i = 0; i < 4; i++)
            af[i] = *(const short8*)&As[(wr * 64 + i * 16 + m16) * 32 + quad * 8];
        #pragma unroll
        for (int j = 0; j < 4; j++)
            bf[j] = *(const short8*)&Bs[(wc * 64 + j * 16 + m16) * 32 + quad * 8];

        // swapped operands: D[n][m] layout -> lane holds row m16, cols quad*4+r
        #pragma unroll
        for (int i = 0; i < 4; i++)
            #pragma unroll
            for (int j = 0; j < 4; j++)
                acc[i][j] = __builtin_amdgcn_mfma_f32_16x16x32_bf16(
                    bf[j], af[i], acc[i][j], 0, 0, 0);
    }

    // Epilogue: row = bm0+wr*64+i*16+m16, cols = bn0+wc*64+j*16+quad*4 .. +3
    float4 bias4[4];
    #pragma unroll
    for (int j = 0; j < 4; j++)
        bias4[j] = *(const float4*)(bias + bn0 + wc * 64 + j * 16 + quad * 4);

    #pragma unroll
    for (int i = 0; i < 4; i++) {
        int row = bm0 + wr * 64 + i * 16 + m16;
        #pragma unroll
        for (int j = 0; j < 4; j++) {
            int col = bn0 + wc * 64 + j * 16 + quad * 4;
            float v0 = acc[i][j][0] + bias4[j].x;
            float v1 = acc[i][j][1] + bias4[j].y;
            float v2 = acc[i][j][2] + bias4[j].z;
            float v3 = acc[i][j][3] + bias4[j].w;
            if (HAS_RES) {
                float4 rr = *(const float4*)(res + (size_t)row * N + col);
                v0 += rr.x; v1 += rr.y; v2 += rr.z; v3 += rr.w;
            }
            if (RELU) {
                v0 = fmaxf(v0, 0.0f); v1 = fmaxf(v1, 0.0f);
                v2 = fmaxf(v2, 0.0f); v3 = fmaxf(v3, 0.0f);
            }
            if (OUT == 0) {
                float4 o = {v0, v1, v2, v3};
                *(float4*)((float*)Cout + (size_t)row * N + col) = o;
            } else if (OUT == 1) {
                ushort4 o;
                o.x = f2bf(v0); o.y = f2bf(v1); o.z = f2bf(v2); o.w = f2bf(v3);
                *(ushort4*)((unsigned short*)Cout + (size_t)row * N + col) = o;
            } else {
                ushort4 o;
                o.x = __half_as_ushort(__float2half_rn(v0));
                o.y = __half_as_ushort(__float2half_rn(v1));
                o.z = __half_as_ushort(__float2half_rn(v2));
                o.w = __half_as_ushort(__float2half_rn(v3));
                *(ushort4*)((unsigned short*)Cout + (size_t)row * N + col) = o;
            }
        }
    }
}

// ---------------------------------------------------------------------------
// MS-deformable sampling. Block = 256 threads = 8 tokens.
// Thread: tt=t>>5 (token), h=(t>>2)&7, q=t&3.
// Phase 1: thread (tt,h,q) computes level q's 4 points -> 16 corner
// (byteoffset, packed-half2-weight) entries into padded LDS table.
// Phase 2: thread gathers 8 channels (q*8..+8) of head h over all 64 corners
// with v_pk_fma_f16.
// ---------------------------------------------------------------------------
__global__ __launch_bounds__(256) void msdeform_kernel(
    const unsigned short* __restrict__ value_h, // (B,SEQ,256) fp16
    const float* __restrict__ oa,               // (MTOK,384): off|attn
    const float* __restrict__ ref,              // (MTOK,8)
    unsigned short* __restrict__ samp_out)      // (MTOK,256) bf16
{
    const int Hs[NLVL] = {64, 32, 16, 8};
    const int Ws[NLVL] = {64, 32, 16, 8};
    const int St[NLVL] = {0, 4096, 5120, 5376};

    const int t  = threadIdx.x;
    const int tt = t >> 5;
    const int rr = t & 31;
    const int h  = rr >> 2;
    const int q  = rr & 3;
    const int token = blockIdx.x * 8 + tt;
    const int b = token / SEQ;

    __shared__ float s_attn[8][8][17];   // padded: bank-spread across (tt,h)
    __shared__ uint2 s_tab[8][8][65];    // 64 entries + pad

    const float* oat = oa + (size_t)token * 384;
    float4 a4 = *(const float4*)(oat + 256 + h * 16 + q * 4);
    s_attn[tt][h][q * 4 + 0] = a4.x;
    s_attn[tt][h][q * 4 + 1] = a4.y;
    s_attn[tt][h][q * 4 + 2] = a4.z;
    s_attn[tt][h][q * 4 + 3] = a4.w;
    float4 o0 = *(const float4*)(oat + h * 32 + q * 8);
    float4 o1 = *(const float4*)(oat + h * 32 + q * 8 + 4);
    float2 rf = *(const float2*)(ref + (size_t)token * 8 + q * 2);
    __syncthreads();

    // softmax (each of the 4 q-threads redundantly computes m, sum)
    float mx = -1e30f;
    #pragma unroll
    for (int i = 0; i < 16; i++) mx = fmaxf(mx, s_attn[tt][h][i]);
    float sum = 0.0f;
    #pragma unroll
    for (int i = 0; i < 16; i++) sum += __expf(s_attn[tt][h][i] - mx);
    float inv = 1.0f / sum;

    // corner table for level q's 4 points
    {
        const int Hl = Hs[q], Wl = Ws[q], s0 = St[q];
        const float fW = (float)Wl, fH = (float)Hl;
        #pragma unroll
        for (int p = 0; p < 4; p++) {
            float ox = (p == 0) ? o0.x : (p == 1) ? o0.z : (p == 2) ? o1.x : o1.z;
            float oy = (p == 0) ? o0.y : (p == 1) ? o0.w : (p == 2) ? o1.y : o1.w;
            float aw = __expf(s_attn[tt][h][q * 4 + p] - mx) * inv;
            float x = (rf.x + ox / fW) * fW - 0.5f;
            float y = (rf.y + oy / fH) * fH - 0.5f;
            float x0f = floorf(x), y0f = floorf(y);
            float wx1 = x - x0f, wy1 = y - y0f;
            float wx0 = 1.0f - wx1, wy0 = 1.0f - wy1;
            int x0 = (int)x0f, y0 = (int)y0f;
            #pragma unroll
            for (int cy = 0; cy < 2; cy++) {
                int yi = y0 + cy;
                bool vy = (yi >= 0) && (yi < Hl);
                int yc = min(max(yi, 0), Hl - 1);
                float wy = cy ? wy1 : wy0;
                #pragma unroll
                for (int cx = 0; cx < 2; cx++) {
                    int xi = x0 + cx;
                    bool vx = (xi >= 0) && (xi < Wl);
                    int xc = min(max(xi, 0), Wl - 1);
                    float w = aw * wy * (cx ? wx1 : wx0) * ((vx && vy) ? 1.0f : 0.0f);
                    unsigned int off = (unsigned int)(s0 + yc * Wl + xc) * 512u;
                    unsigned short hw = __half_as_ushort(__float2half_rn(w));
                    unsigned int wp = (unsigned int)hw | ((unsigned int)hw << 16);
                    s_tab[tt][h][(q * 4 + p) * 4 + cy * 2 + cx] = make_uint2(off, wp);
                }
            }
        }
    }
    __syncthreads();

    // gather: 8 channels per thread over 64 corners
    const char* vb = (const char*)value_h;
    unsigned int cbase = (unsigned int)(b * (SEQ * 512)) + h * 64 + q * 16;
    const uint2* tab = &s_tab[tt][h][0];

    __half2 z; { union { unsigned int u; __half2 h; } c; c.u = 0; z = c.h; }
    __half2 acc0 = z, acc1 = z, acc2 = z, acc3 = z;

    #pragma unroll 16
    for (int i = 0; i < 64; i++) {
        uint2 e = tab[i];
        uint4 v = *(const uint4*)(vb + (cbase + e.x));
        union { unsigned int u; __half2 h; } wu; wu.u = e.y;
        union { uint4 u; __half2 h[4]; } vu; vu.u = v;
        acc0 = __hfma2(vu.h[0], wu.h, acc0);
        acc1 = __hfma2(vu.h[1], wu.h, acc1);
        acc2 = __hfma2(vu.h[2], wu.h, acc2);
        acc3 = __hfma2(vu.h[3], wu.h, acc3);
    }

    uint4 o;
    o.x = (unsigned int)f2bf(__low2float(acc0)) | ((unsigned int)f2bf(__high2float(acc0)) << 16);
    o.y = (unsigned int)f2bf(__low2float(acc1)) | ((unsigned int)f2bf(__high2float(acc1)) << 16);
    o.z = (unsigned int)f2bf(__low2float(acc2)) | ((unsigned int)f2bf(__high2float(acc2)) << 16);
    o.w = (unsigned int)f2bf(__low2float(acc3)) | ((unsigned int)f2bf(__high2float(acc3)) << 16);
    *(uint4*)(samp_out + (size_t)token * 256 + h * 32 + q * 8) = o;
}

// ---------------------------------------------------------------------------
// Launch
// ---------------------------------------------------------------------------
extern "C" void kernel_launch(void* const* d_in, const int* in_sizes, int n_in,
                              void* d_out, int out_size, void* d_ws, size_t ws_size,
                              hipStream_t stream) {
    const float* input = (const float*)d_in[0];
    const float* pos   = (const float*)d_in[1];
    const float* ref   = (const float*)d_in[2];
    const float* ln1_w = (const float*)d_in[5];
    const float* ln1_b = (const float*)d_in[6];
    const float* W_off = (const float*)d_in[7];
    const float* b_off = (const float*)d_in[8];
    const float* W_attn = (const float*)d_in[9];
    const float* b_attn = (const float*)d_in[10];
    const float* W_val = (const float*)d_in[11];
    const float* b_val = (const float*)d_in[12];
    const float* W_out = (const float*)d_in[13];
    const float* b_out = (const float*)d_in[14];
    const float* ln2_w = (const float*)d_in[15];
    const float* ln2_b = (const float*)d_in[16];
    const float* ff_w1 = (const float*)d_in[17];
    const float* ff_b1 = (const float*)d_in[18];
    const float* ff_w2 = (const float*)d_in[19];
    const float* ff_b2 = (const float*)d_in[20];
    float* out = (float*)d_out;

    const size_t M = MTOK;
    float* ws = (float*)d_ws;

    // Workspace (float units):
    unsigned short* input_bf = (unsigned short*)(ws);              // M*128f
    unsigned short* y_bf     = input_bf;                           // reuse
    unsigned short* q_bf     = (unsigned short*)(ws + M * 128);    // M*128f
    unsigned short* samp_bf  = q_bf;                               // reuse
    float*  oa_buf   = ws + M * 256;                               // M*384f
    float*  x_buf    = oa_buf;                                     // reuse
    unsigned short* val_h = (unsigned short*)(ws + M * 640);       // M*128f
    unsigned short* h_bf  = (unsigned short*)(ws + M * 768);       // M*512f
    unsigned short* wts   = (unsigned short*)(ws + M * 1280);      // 753664 us
    float* bcomb = (float*)(wts + 753664);                         // 384 f

    unsigned short* wval_t  = wts;
    unsigned short* woff_t  = wval_t  + 256 * 256;   // [woff|wattn] = N=384
    unsigned short* wout_t  = woff_t  + 384 * 256;
    unsigned short* ffw1_t  = wout_t  + 256 * 256;
    unsigned short* ffw2_t  = ffw1_t  + 1024 * 256;

    dim3 blk(256);

    // 0) weight prep + combined bias
    wtprep_kernel<<<dim3(2944), blk, 0, stream>>>(
        W_val, W_off, W_attn, W_out, ff_w1, ff_w2, b_off, b_attn, wts, bcomb);

    // 1) q = LN1(input)+pos (bf16); input_bf = bf16(input)
    ln_kernel<1><<<dim3(M / 4), blk, 0, stream>>>(
        input, ln1_w, ln1_b, pos, q_bf, input_bf);

    // 2) value = input @ W_val + b_val -> fp16
    mfma_gemm<256, 2, 0, 0><<<dim3(2, M / 128), blk, 0, stream>>>(
        input_bf, wval_t, b_val, nullptr, val_h, M, 256);

    // 3) [off|attn] = q @ [W_off|W_attn] + bcomb -> fp32 (N=384)
    mfma_gemm<256, 0, 0, 0><<<dim3(3, M / 128), blk, 0, stream>>>(
        q_bf, woff_t, bcomb, nullptr, oa_buf, M, 384);

    // 4) sampling -> samp (bf16)
    msdeform_kernel<<<dim3(M / 8), blk, 0, stream>>>(
        val_h, oa_buf, ref, samp_bf);

    // 5) x = input + samp @ W_out + b_out -> fp32
    mfma_gemm<256, 0, 0, 1><<<dim3(2, M / 128), blk, 0, stream>>>(
        samp_bf, wout_t, b_out, input, x_buf, M, 256);

    // 6) y = LN2(x) -> bf16
    ln_kernel<0><<<dim3(M / 4), blk, 0, stream>>>(
        x_buf, ln2_w, ln2_b, nullptr, y_bf, nullptr);

    // 7) h = relu(y @ ff_w1 + ff_b1) -> bf16
    mfma_gemm<256, 1, 1, 0><<<dim3(8, M / 128), blk, 0, stream>>>(
        y_bf, ffw1_t, ff_b1, nullptr, h_bf, M, 1024);

    // 8) out = x + h @ ff_w2 + ff_b2 -> fp32
    mfma_gemm<1024, 0, 0, 1><<<dim3(2, M / 128), blk, 0, stream>>>(
        h_bf, ffw2_t, ff_b2, x_buf, out, M, 256);
}